// Round 7
// baseline (442.016 us; speedup 1.0000x reference)
//
#include <hip/hip_runtime.h>
#include <hip/hip_bf16.h>

// GRNNTransformGated, round 6.
//  - u_all precomputed for ALL 524224 rows in one grid-parallel kernel;
//    level tiles stage u with uint4 copies (kills ~500 VALU instr/thread that
//    round-5 spent computing u in-tile -- tiles were issue-bound, not
//    epilogue-bound: 48K cyc/tile vs 5K work, VALUBusy 39%).
//  - In-place up: level j's gated output overwrites u_all's level-j region
//    (u dead after staging; WAR ordered by barriers). ws = 67 MB.
//  - exp2-folded weights: W_r/b_r/W_z/b_z pre-scaled by log2e at pack time;
//    sigmoid = rcp(1+exp2(-y)), softmax = exp2 without max-sub.
//  - Tail fusion via NESTED SLICES: block b owns fraction [b/B,(b+1)/B) of
//    every level; its level-j reads are its own level-(j+1) writes -> levels
//    chain with __syncthreads only, NO grid barrier (round-4: agent-scope
//    spin barriers cost ~137us each -- never again). fused_mid: j=8..2
//    (B=256); fused_tail: j=1..0 (B=2). 7 launches total.
// Operand-swapped MFMA (round 4): D = W @ act^T; A/B frags of
// mfma_f32_16x16x32_bf16 share one lane map; C gives each lane 4 consecutive
// out-cols of one row -> b64 epilogues.

#define LOG2E 1.4426950408889634f

typedef __bf16 bf16x8 __attribute__((ext_vector_type(8)));
typedef float f32x4 __attribute__((ext_vector_type(4)));
typedef unsigned short bfr;   // raw bf16 bits

__device__ __forceinline__ float bfr2f(bfr v) { return __uint_as_float(((unsigned)v) << 16); }
__device__ __forceinline__ bfr f2bfr(float f) {
    __hip_bfloat16 h = __float2bfloat16(f);
    return __builtin_bit_cast(bfr, h);
}
__device__ __forceinline__ float fexp2(float x) {
#if __has_builtin(__builtin_amdgcn_exp2f)
    return __builtin_amdgcn_exp2f(x);
#else
    return exp2f(x);
#endif
}
__device__ __forceinline__ float frcp(float x) {
#if __has_builtin(__builtin_amdgcn_rcpf)
    return __builtin_amdgcn_rcpf(x);
#else
    return 1.f / x;
#endif
}

// fragment-order address (elements): frag (Mt,kt), lane (ln,q), 8 elems
__device__ __forceinline__ int fidx(int Mt, int kt, int q, int ln, int KT) {
    return ((((Mt * KT + kt) * 4 + q) * 16 + ln) * 8);
}

// level-j region start (elements) within u_all: rows 64*(2^j-1), 64 cols
__device__ __host__ __forceinline__ size_t lvloff(int j) {
    return (size_t)((64 << j) - 64) * 64;
}

__device__ __forceinline__ void pack_one(const float* __restrict__ W, bfr* __restrict__ dst,
                                         int d, int K, float scale) {
    int KT = K >> 5;
    int j = d & 7, lnc = (d >> 3) & 15, q = (d >> 7) & 3;
    int t1 = d >> 9;
    int kt = t1 % KT, ntile = t1 / KT;
    int ncol = ntile * 16 + lnc;
    int k = kt * 32 + q * 8 + j;
    dst[d] = f2bfr(W[(size_t)ncol * K + k] * scale);
}

__global__ void convert_weights(const float* __restrict__ Wr, const float* __restrict__ Wh,
                                const float* __restrict__ Wz,
                                const float* __restrict__ br, const float* __restrict__ bz,
                                bfr* __restrict__ wr, bfr* __restrict__ wh, bfr* __restrict__ wz,
                                float* __restrict__ brs, float* __restrict__ bzs) {
    int i = blockIdx.x * 256 + threadIdx.x;   // grid covers 65536
    if (i < 36864) pack_one(Wr, wr, i, 192, LOG2E);
    if (i < 12288) pack_one(Wh, wh, i, 192, 1.f);
    if (i < 65536) pack_one(Wz, wz, i, 256, LOG2E);
    if (i < 192) brs[i] = br[i] * LOG2E;
    if (i < 256) bzs[i] = bz[i] * LOG2E;
}

// u = relu(contents @ W_u^T + b_u) for ALL rows. thread -> (row, 8-col octet).
__global__ void u_kernel(const float* __restrict__ contents,
                         const float* __restrict__ W_u, const float* __restrict__ b_u,
                         bfr* __restrict__ u_all) {
    int t = blockIdx.x * 256 + threadIdx.x;   // grid*256 == 524224*8 exactly
    int row = t >> 3, o0 = (t & 7) * 8;
    float wv[56];
#pragma unroll
    for (int p = 0; p < 14; ++p)
        *(float4*)&wv[p * 4] = *(const float4*)&W_u[o0 * 7 + p * 4];
    float c[7];
    const float* cp = contents + (size_t)row * 7;
#pragma unroll
    for (int k = 0; k < 7; ++k) c[k] = cp[k];
    ushort tmp[8];
#pragma unroll
    for (int jj = 0; jj < 8; ++jj) {
        float acc = b_u[o0 + jj];
#pragma unroll
        for (int k = 0; k < 7; ++k) acc += c[k] * wv[jj * 7 + k];
        tmp[jj] = f2bfr(fmaxf(acc, 0.f));
    }
    *(uint4*)&u_all[(size_t)row * 64 + o0] = *(const uint4*)tmp;
}

// One level-slice: rows `rows` (<=64) starting at level-row `row0`.
// ch   = children up region (level j+1), reads rows [2*row0, 2*row0+2*rows)
// u_io = level-j region: staging READS u rows [row0,row0+rows); mm3 WRITES
//        the gated up to the same rows (in-place, WAR ordered by barriers).
__device__ __forceinline__ void process_level(
    int row0, int rows,
    const bfr* __restrict__ ch, bfr* __restrict__ u_io,
    const bfr* __restrict__ wr, const float* __restrict__ brs,
    const bfr* __restrict__ wh, const float* __restrict__ b_h,
    const bfr* __restrict__ wz, const float* __restrict__ bzs,
    float* __restrict__ outp,
    bfr* s_hhu, bfr* s_t)
{
    bfr* s_hH = s_t;   // aliased; h_H written only after all s_t reads done
    const int tid = threadIdx.x;
    const int lane = tid & 63, w = tid >> 6;
    const int ln = lane & 15, q = lane >> 4;
    const int Mtn = (rows + 15) >> 4;

    __syncthreads();   // protect s_hhu/s_t against previous level's readers

    // ---- stage hhu in fragment order: cols 0..127 from children, 128..191 from u ----
#pragma unroll
    for (int it = 0; it < 6; ++it) {
        int idx = it * 256 + tid;
        if (it < 4) {
            int lns = idx & 15, qs = (idx >> 4) & 3, kts = (idx >> 6) & 3, Mts = idx >> 8;
            int row = Mts * 16 + lns;
            if (row < rows) {
                int k = kts * 32 + qs * 8;
                const bfr* src = (k < 64)
                    ? ch + (size_t)(2 * (row0 + row)) * 64 + k
                    : ch + (size_t)(2 * (row0 + row) + 1) * 64 + (k - 64);
                *(uint4*)&s_hhu[fidx(Mts, kts, qs, lns, 6)] = *(const uint4*)src;
            }
        } else {
            int idx2 = idx - 1024;
            int lns = idx2 & 15, qs = (idx2 >> 4) & 3, ktl = (idx2 >> 6) & 1, Mts = (idx2 >> 7) & 3;
            int row = Mts * 16 + lns;
            if (row < rows) {
                int o0 = ktl * 32 + qs * 8;
                *(uint4*)&s_hhu[fidx(Mts, 4 + ktl, qs, lns, 6)] =
                    *(const uint4*)&u_io[(size_t)(row0 + row) * 64 + o0];
            }
        }
    }
    __syncthreads();

    // ---- mm1: D = W_r' @ hhu^T ; t = rcp(1+exp2(-y)) * hhu ----
#pragma unroll
    for (int nt = 0; nt < 3; ++nt) {
        int ntile = w * 3 + nt;
        bf16x8 Af[6];
#pragma unroll
        for (int kt = 0; kt < 6; ++kt)
            Af[kt] = *(const bf16x8*)&wr[fidx(ntile, kt, q, ln, 6)];
        int colbase = ntile * 16 + q * 4;
        f32x4 br4 = *(const f32x4*)&brs[colbase];
#pragma unroll
        for (int Mt = 0; Mt < 4; ++Mt) {
            if (Mt < Mtn) {
                f32x4 acc = {0.f, 0.f, 0.f, 0.f};
#pragma unroll
                for (int kt = 0; kt < 6; ++kt) {
                    bf16x8 Bf = *(const bf16x8*)&s_hhu[fidx(Mt, kt, q, ln, 6)];
                    acc = __builtin_amdgcn_mfma_f32_16x16x32_bf16(Af[kt], Bf, acc, 0, 0, 0);
                }
                int addr = fidx(Mt, colbase >> 5, (colbase >> 3) & 3, ln, 6) + (colbase & 7);
                ushort hh[4], tt[4];
                *(uint2*)hh = *(const uint2*)&s_hhu[addr];
#pragma unroll
                for (int r = 0; r < 4; ++r) {
                    float e = fexp2(-(acc[r] + br4[r]));
                    float sg = frcp(1.f + e);
                    tt[r] = f2bfr(sg * bfr2f(hh[r]));
                }
                *(uint2*)&s_t[addr] = *(const uint2*)tt;
            }
        }
    }
    __syncthreads();

    // ---- mm2: D = W_h @ t^T (to regs), then store h_H into aliased LDS ----
    f32x4 hacc[4];
    {
        bf16x8 Ah[6];
#pragma unroll
        for (int kt = 0; kt < 6; ++kt)
            Ah[kt] = *(const bf16x8*)&wh[fidx(w, kt, q, ln, 6)];
#pragma unroll
        for (int Mt = 0; Mt < 4; ++Mt) {
            if (Mt < Mtn) {
                f32x4 acc = {0.f, 0.f, 0.f, 0.f};
#pragma unroll
                for (int kt = 0; kt < 6; ++kt) {
                    bf16x8 Bf = *(const bf16x8*)&s_t[fidx(Mt, kt, q, ln, 6)];
                    acc = __builtin_amdgcn_mfma_f32_16x16x32_bf16(Ah[kt], Bf, acc, 0, 0, 0);
                }
                hacc[Mt] = acc;
            }
        }
    }
    __syncthreads();   // all s_t reads complete -> safe to overwrite (s_hH alias)
    {
        int colbase = w * 16 + q * 4;
        f32x4 bh4 = *(const f32x4*)&b_h[colbase];
#pragma unroll
        for (int Mt = 0; Mt < 4; ++Mt) {
            if (Mt < Mtn) {
                int addr = fidx(Mt, colbase >> 5, (colbase >> 3) & 3, ln, 2) + (colbase & 7);
                ushort hv[4];
#pragma unroll
                for (int r = 0; r < 4; ++r) hv[r] = f2bfr(fmaxf(hacc[Mt][r] + bh4[r], 0.f));
                *(uint2*)&s_hH[addr] = *(const uint2*)hv;
            }
        }
    }
    __syncthreads();

    // ---- mm3: D = W_z' @ [h_H,hhu]^T ; softmax-4 (exp2, no max-sub) gate ----
    {
        f32x4 az[4][4];
#pragma unroll
        for (int Mt = 0; Mt < 4; ++Mt)
#pragma unroll
            for (int g = 0; g < 4; ++g) az[Mt][g] = (f32x4){0.f, 0.f, 0.f, 0.f};
#pragma unroll
        for (int g = 0; g < 4; ++g) {
            int ntile = g * 4 + w;
            bf16x8 Aw[8];
#pragma unroll
            for (int kt = 0; kt < 8; ++kt)
                Aw[kt] = *(const bf16x8*)&wz[fidx(ntile, kt, q, ln, 8)];
#pragma unroll
            for (int Mt = 0; Mt < 4; ++Mt) {
                if (Mt < Mtn) {
                    f32x4 acc = az[Mt][g];
                    acc = __builtin_amdgcn_mfma_f32_16x16x32_bf16(
                        Aw[0], *(const bf16x8*)&s_hH[fidx(Mt, 0, q, ln, 2)], acc, 0, 0, 0);
                    acc = __builtin_amdgcn_mfma_f32_16x16x32_bf16(
                        Aw[1], *(const bf16x8*)&s_hH[fidx(Mt, 1, q, ln, 2)], acc, 0, 0, 0);
#pragma unroll
                    for (int kt = 0; kt < 6; ++kt)
                        acc = __builtin_amdgcn_mfma_f32_16x16x32_bf16(
                            Aw[2 + kt], *(const bf16x8*)&s_hhu[fidx(Mt, kt, q, ln, 6)], acc, 0, 0, 0);
                    az[Mt][g] = acc;
                }
            }
        }
        int colbase = w * 16 + q * 4;
        f32x4 bz0 = *(const f32x4*)&bzs[colbase];
        f32x4 bz1 = *(const f32x4*)&bzs[64 + colbase];
        f32x4 bz2 = *(const f32x4*)&bzs[128 + colbase];
        f32x4 bz3 = *(const f32x4*)&bzs[192 + colbase];
#pragma unroll
        for (int Mt = 0; Mt < 4; ++Mt) {
            if (Mt < Mtn) {
                int aH = fidx(Mt, colbase >> 5, (colbase >> 3) & 3, ln, 2) + (colbase & 7);
                int a0 = fidx(Mt, colbase >> 5, (colbase >> 3) & 3, ln, 6) + (colbase & 7);
                int c1 = 64 + colbase, c2 = 128 + colbase;
                int a1 = fidx(Mt, c1 >> 5, (c1 >> 3) & 3, ln, 6) + (c1 & 7);
                int a2 = fidx(Mt, c2 >> 5, (c2 >> 3) & 3, ln, 6) + (c2 & 7);
                int row = Mt * 16 + ln;
                if (row < rows) {
                    ushort hHv[4], u0[4], u1[4], u2[4];
                    *(uint2*)hHv = *(const uint2*)&s_hH[aH];
                    *(uint2*)u0 = *(const uint2*)&s_hhu[a0];
                    *(uint2*)u1 = *(const uint2*)&s_hhu[a1];
                    *(uint2*)u2 = *(const uint2*)&s_hhu[a2];
                    ushort ov[4]; float of[4];
#pragma unroll
                    for (int r = 0; r < 4; ++r) {
                        float e0 = fexp2(az[Mt][0][r] + bz0[r]);
                        float e1 = fexp2(az[Mt][1][r] + bz1[r]);
                        float e2 = fexp2(az[Mt][2][r] + bz2[r]);
                        float e3 = fexp2(az[Mt][3][r] + bz3[r]);
                        float inv = frcp(e0 + e1 + e2 + e3);
                        float v = (e0 * bfr2f(hHv[r]) + e1 * bfr2f(u0[r]) +
                                   e2 * bfr2f(u1[r]) + e3 * bfr2f(u2[r])) * inv;
                        ov[r] = f2bfr(v); of[r] = v;
                    }
                    size_t grow = (size_t)(row0 + row);
                    *(uint2*)&u_io[grow * 64 + colbase] = *(const uint2*)ov;
                    if (outp) *(float4*)&outp[grow * 64 + colbase] = *(const float4*)of;
                }
            }
        }
    }
}

__global__ __launch_bounds__(256, 3) void level_kernel(
    const bfr* __restrict__ ch, bfr* __restrict__ u_io,
    const bfr* __restrict__ wr, const float* __restrict__ brs,
    const bfr* __restrict__ wh, const float* __restrict__ b_h,
    const bfr* __restrict__ wz, const float* __restrict__ bzs)
{
    __shared__ bfr s_hhu[12288];
    __shared__ bfr s_t[12288];
    process_level(blockIdx.x * 64, 64, ch, u_io, wr, brs, wh, b_h, wz, bzs,
                  nullptr, s_hhu, s_t);
}

// levels j=8..2, B=256 blocks, nested slices: block b's reads at level j are
// exactly its own writes at level j+1 -> no grid sync needed.
__global__ __launch_bounds__(256, 3) void fused_mid(
    bfr* __restrict__ u_all,
    const bfr* __restrict__ wr, const float* __restrict__ brs,
    const bfr* __restrict__ wh, const float* __restrict__ b_h,
    const bfr* __restrict__ wz, const float* __restrict__ bzs)
{
    __shared__ bfr s_hhu[12288];
    __shared__ bfr s_t[12288];
    for (int j = 8; j >= 2; --j) {
        int rows = 1 << (j - 2);
        process_level(blockIdx.x * rows, rows,
                      u_all + lvloff(j + 1), u_all + lvloff(j),
                      wr, brs, wh, b_h, wz, bzs, nullptr, s_hhu, s_t);
    }
}

// levels j=1..0, B=2 blocks.
__global__ __launch_bounds__(256, 3) void fused_tail(
    bfr* __restrict__ u_all,
    const bfr* __restrict__ wr, const float* __restrict__ brs,
    const bfr* __restrict__ wh, const float* __restrict__ b_h,
    const bfr* __restrict__ wz, const float* __restrict__ bzs,
    float* __restrict__ outp)
{
    __shared__ bfr s_hhu[12288];
    __shared__ bfr s_t[12288];
    process_level(blockIdx.x * 64, 64, u_all + lvloff(2), u_all + lvloff(1),
                  wr, brs, wh, b_h, wz, bzs, nullptr, s_hhu, s_t);
    process_level(blockIdx.x * 32, 32, u_all + lvloff(1), u_all + lvloff(0),
                  wr, brs, wh, b_h, wz, bzs, outp, s_hhu, s_t);
}

extern "C" void kernel_launch(void* const* d_in, const int* in_sizes, int n_in,
                              void* d_out, int out_size, void* d_ws, size_t ws_size,
                              hipStream_t stream) {
    const float* contents = (const float*)d_in[0];
    const float* W_u = (const float*)d_in[1];
    const float* b_u = (const float*)d_in[2];
    const float* W_r = (const float*)d_in[3];
    const float* b_r = (const float*)d_in[4];
    const float* W_h = (const float*)d_in[5];
    const float* b_h = (const float*)d_in[6];
    const float* W_z = (const float*)d_in[7];
    const float* b_z = (const float*)d_in[8];
    float* out = (float*)d_out;

    // ws layout: u_all (524224 rows x 64, bf16; levels overwritten in-place
    // with their up) | wr | wh | wz | brs | bzs  -> ~67.3 MB total
    bfr* u_all = (bfr*)d_ws;
    bfr* wr = u_all + (size_t)524224 * 64;   // 33,550,336 elems
    bfr* wh = wr + 36864;
    bfr* wz = wh + 12288;
    float* brs = (float*)(wz + 65536);
    float* bzs = brs + 192;

    convert_weights<<<256, 256, 0, stream>>>(W_r, W_h, W_z, b_r, b_z,
                                             wr, wh, wz, brs, bzs);
    u_kernel<<<16382, 256, 0, stream>>>(contents, W_u, b_u, u_all);  // 524224*8/256

    // big levels: one 64-row tile per block
    level_kernel<<<2048, 256, 0, stream>>>(u_all + lvloff(12), u_all + lvloff(11),
                                           wr, brs, wh, b_h, wz, bzs);
    level_kernel<<<1024, 256, 0, stream>>>(u_all + lvloff(11), u_all + lvloff(10),
                                           wr, brs, wh, b_h, wz, bzs);
    level_kernel<<<512, 256, 0, stream>>>(u_all + lvloff(10), u_all + lvloff(9),
                                          wr, brs, wh, b_h, wz, bzs);
    fused_mid<<<256, 256, 0, stream>>>(u_all, wr, brs, wh, b_h, wz, bzs);
    fused_tail<<<2, 256, 0, stream>>>(u_all, wr, brs, wh, b_h, wz, bzs, out);
}

// Round 8
// 353.165 us; speedup vs baseline: 1.2516x; 1.2516x over previous
//
#include <hip/hip_runtime.h>
#include <hip/hip_bf16.h>

// GRNNTransformGated, round 7.
// Post-mortems driving this version:
//  R4: agent-scope spin grid barriers ~137us each on MI355X -> never.
//  R6: 256-block x 7-level nested fusion refetches weights from HBM (189MB,
//      46% L2 miss; blocks decouple) -> fuse ONLY the tiny tail (B=32,
//      j=5..0, 43MB demand, L2-hot). Big/mid levels: one launch each.
//  R5/R6: float wv[56] private arrays spill to scratch (WRITE 96MB vs 16.8MB
//      data) -> u_kernel restructured to 14 weight floats reused over 4 rows.
//  Tiles are LDS-pipe bound (~224 ds_read_b128/wave vs 224 MFMA) -> mm1
//      restructured: 18 W_r A-frags held in regs, Mt-outer => ds 72->24.
// Carried forward: u_all precompute; in-place up (level j's output overwrites
// its own u region); exp2-folded W_r/b_r/W_z/b_z; operand-swapped MFMA
// (D = W @ act^T; A/B frags of mfma_f32_16x16x32_bf16 share one lane map;
// lane gets 4 consecutive out-cols of one row -> b64 epilogues).

#define LOG2E 1.4426950408889634f

typedef __bf16 bf16x8 __attribute__((ext_vector_type(8)));
typedef float f32x4 __attribute__((ext_vector_type(4)));
typedef unsigned short bfr;   // raw bf16 bits

__device__ __forceinline__ float bfr2f(bfr v) { return __uint_as_float(((unsigned)v) << 16); }
__device__ __forceinline__ bfr f2bfr(float f) {
    __hip_bfloat16 h = __float2bfloat16(f);
    return __builtin_bit_cast(bfr, h);
}
__device__ __forceinline__ float fexp2(float x) {
#if __has_builtin(__builtin_amdgcn_exp2f)
    return __builtin_amdgcn_exp2f(x);
#else
    return exp2f(x);
#endif
}
__device__ __forceinline__ float frcp(float x) {
#if __has_builtin(__builtin_amdgcn_rcpf)
    return __builtin_amdgcn_rcpf(x);
#else
    return 1.f / x;
#endif
}

// fragment-order address (elements): frag (Mt,kt), lane (ln,q), 8 elems
__device__ __forceinline__ int fidx(int Mt, int kt, int q, int ln, int KT) {
    return ((((Mt * KT + kt) * 4 + q) * 16 + ln) * 8);
}

// level-j region start (elements) within u_all: rows 64*(2^j-1), 64 cols
__device__ __host__ __forceinline__ size_t lvloff(int j) {
    return (size_t)((64 << j) - 64) * 64;
}

__device__ __forceinline__ void pack_one(const float* __restrict__ W, bfr* __restrict__ dst,
                                         int d, int K, float scale) {
    int KT = K >> 5;
    int j = d & 7, lnc = (d >> 3) & 15, q = (d >> 7) & 3;
    int t1 = d >> 9;
    int kt = t1 % KT, ntile = t1 / KT;
    int ncol = ntile * 16 + lnc;
    int k = kt * 32 + q * 8 + j;
    dst[d] = f2bfr(W[(size_t)ncol * K + k] * scale);
}

__global__ void convert_weights(const float* __restrict__ Wr, const float* __restrict__ Wh,
                                const float* __restrict__ Wz,
                                const float* __restrict__ br, const float* __restrict__ bz,
                                bfr* __restrict__ wr, bfr* __restrict__ wh, bfr* __restrict__ wz,
                                float* __restrict__ brs, float* __restrict__ bzs) {
    int i = blockIdx.x * 256 + threadIdx.x;   // grid covers 65536
    if (i < 36864) pack_one(Wr, wr, i, 192, LOG2E);
    if (i < 12288) pack_one(Wh, wh, i, 192, 1.f);
    if (i < 65536) pack_one(Wz, wz, i, 256, LOG2E);
    if (i < 192) brs[i] = br[i] * LOG2E;
    if (i < 256) bzs[i] = bz[i] * LOG2E;
}

// u = relu(contents @ W_u^T + b_u) for ALL 524224 rows.
// thread -> 2 output cols x 4 rows: only 14 weight floats live (no spill),
// weights reused 4x, stores coalesced (consecutive lanes -> consecutive col
// pairs of the same row).
__global__ void u_kernel(const float* __restrict__ contents,
                         const float* __restrict__ W_u, const float* __restrict__ b_u,
                         bfr* __restrict__ u_all) {
    int t = blockIdx.x * 256 + threadIdx.x;   // 16382*256 == 524224/4*32
    int row0 = (t >> 5) * 4, o0 = (t & 31) * 2;
    float w0[7], w1[7];
#pragma unroll
    for (int k = 0; k < 7; ++k) { w0[k] = W_u[o0 * 7 + k]; w1[k] = W_u[o0 * 7 + 7 + k]; }
    float bb0 = b_u[o0], bb1 = b_u[o0 + 1];
#pragma unroll
    for (int rr = 0; rr < 4; ++rr) {
        const float* cp = contents + (size_t)(row0 + rr) * 7;
        float a0 = bb0, a1 = bb1;
#pragma unroll
        for (int k = 0; k < 7; ++k) { float c = cp[k]; a0 += c * w0[k]; a1 += c * w1[k]; }
        ushort2 uv;
        uv.x = f2bfr(fmaxf(a0, 0.f));
        uv.y = f2bfr(fmaxf(a1, 0.f));
        *(ushort2*)&u_all[(size_t)(row0 + rr) * 64 + o0] = uv;
    }
}

// One level-slice: rows `rows` (<=64) starting at level-row `row0`.
// ch   = children up region (level j+1), reads rows [2*row0, 2*row0+2*rows)
// u_io = level-j region: staging READS u rows [row0,row0+rows); mm3 WRITES
//        the gated up to the same rows (in-place, WAR ordered by barriers).
__device__ __forceinline__ void process_level(
    int row0, int rows,
    const bfr* __restrict__ ch, bfr* __restrict__ u_io,
    const bfr* __restrict__ wr, const float* __restrict__ brs,
    const bfr* __restrict__ wh, const float* __restrict__ b_h,
    const bfr* __restrict__ wz, const float* __restrict__ bzs,
    float* __restrict__ outp,
    bfr* s_hhu, bfr* s_t)
{
    bfr* s_hH = s_t;   // aliased; h_H written only after all s_t reads done
    const int tid = threadIdx.x;
    const int lane = tid & 63, w = tid >> 6;
    const int ln = lane & 15, q = lane >> 4;
    const int Mtn = (rows + 15) >> 4;

    __syncthreads();   // protect s_hhu/s_t against previous level's readers

    // ---- stage hhu in fragment order: cols 0..127 from children, 128..191 from u ----
#pragma unroll
    for (int it = 0; it < 6; ++it) {
        int idx = it * 256 + tid;
        if (it < 4) {
            int lns = idx & 15, qs = (idx >> 4) & 3, kts = (idx >> 6) & 3, Mts = idx >> 8;
            int row = Mts * 16 + lns;
            if (row < rows) {
                int k = kts * 32 + qs * 8;
                const bfr* src = (k < 64)
                    ? ch + (size_t)(2 * (row0 + row)) * 64 + k
                    : ch + (size_t)(2 * (row0 + row) + 1) * 64 + (k - 64);
                *(uint4*)&s_hhu[fidx(Mts, kts, qs, lns, 6)] = *(const uint4*)src;
            }
        } else {
            int idx2 = idx - 1024;
            int lns = idx2 & 15, qs = (idx2 >> 4) & 3, ktl = (idx2 >> 6) & 1, Mts = (idx2 >> 7) & 3;
            int row = Mts * 16 + lns;
            if (row < rows) {
                int o0 = ktl * 32 + qs * 8;
                *(uint4*)&s_hhu[fidx(Mts, 4 + ktl, qs, lns, 6)] =
                    *(const uint4*)&u_io[(size_t)(row0 + row) * 64 + o0];
            }
        }
    }
    __syncthreads();

    // ---- mm1: D = W_r' @ hhu^T ; t = rcp(1+exp2(-y)) * hhu ----
    // 18 A-frags (weights) held in regs; Mt-outer => 24 ds_read_b128 not 72.
    {
        bf16x8 Af[3][6];
#pragma unroll
        for (int nt = 0; nt < 3; ++nt)
#pragma unroll
            for (int kt = 0; kt < 6; ++kt)
                Af[nt][kt] = *(const bf16x8*)&wr[fidx(w * 3 + nt, kt, q, ln, 6)];
#pragma unroll
        for (int Mt = 0; Mt < 4; ++Mt) {
            if (Mt < Mtn) {
                bf16x8 Bf[6];
#pragma unroll
                for (int kt = 0; kt < 6; ++kt)
                    Bf[kt] = *(const bf16x8*)&s_hhu[fidx(Mt, kt, q, ln, 6)];
#pragma unroll
                for (int nt = 0; nt < 3; ++nt) {
                    int colbase = (w * 3 + nt) * 16 + q * 4;
                    f32x4 acc = {0.f, 0.f, 0.f, 0.f};
#pragma unroll
                    for (int kt = 0; kt < 6; ++kt)
                        acc = __builtin_amdgcn_mfma_f32_16x16x32_bf16(Af[nt][kt], Bf[kt], acc, 0, 0, 0);
                    f32x4 br4 = *(const f32x4*)&brs[colbase];
                    int addr = fidx(Mt, colbase >> 5, (colbase >> 3) & 3, ln, 6) + (colbase & 7);
                    ushort hh[4], tt[4];
                    *(uint2*)hh = *(const uint2*)&s_hhu[addr];
#pragma unroll
                    for (int r = 0; r < 4; ++r) {
                        float e = fexp2(-(acc[r] + br4[r]));
                        float sg = frcp(1.f + e);
                        tt[r] = f2bfr(sg * bfr2f(hh[r]));
                    }
                    *(uint2*)&s_t[addr] = *(const uint2*)tt;
                }
            }
        }
    }
    __syncthreads();

    // ---- mm2: D = W_h @ t^T (to regs), then store h_H into aliased LDS ----
    f32x4 hacc[4];
    {
        bf16x8 Ah[6];
#pragma unroll
        for (int kt = 0; kt < 6; ++kt)
            Ah[kt] = *(const bf16x8*)&wh[fidx(w, kt, q, ln, 6)];
#pragma unroll
        for (int Mt = 0; Mt < 4; ++Mt) {
            if (Mt < Mtn) {
                f32x4 acc = {0.f, 0.f, 0.f, 0.f};
#pragma unroll
                for (int kt = 0; kt < 6; ++kt) {
                    bf16x8 Bf = *(const bf16x8*)&s_t[fidx(Mt, kt, q, ln, 6)];
                    acc = __builtin_amdgcn_mfma_f32_16x16x32_bf16(Ah[kt], Bf, acc, 0, 0, 0);
                }
                hacc[Mt] = acc;
            }
        }
    }
    __syncthreads();   // all s_t reads complete -> safe to overwrite (s_hH alias)
    {
        int colbase = w * 16 + q * 4;
        f32x4 bh4 = *(const f32x4*)&b_h[colbase];
#pragma unroll
        for (int Mt = 0; Mt < 4; ++Mt) {
            if (Mt < Mtn) {
                int addr = fidx(Mt, colbase >> 5, (colbase >> 3) & 3, ln, 2) + (colbase & 7);
                ushort hv[4];
#pragma unroll
                for (int r = 0; r < 4; ++r) hv[r] = f2bfr(fmaxf(hacc[Mt][r] + bh4[r], 0.f));
                *(uint2*)&s_hH[addr] = *(const uint2*)hv;
            }
        }
    }
    __syncthreads();

    // ---- mm3: D = W_z' @ [h_H,hhu]^T ; softmax-4 (exp2, no max-sub) gate ----
    {
        f32x4 az[4][4];
#pragma unroll
        for (int Mt = 0; Mt < 4; ++Mt)
#pragma unroll
            for (int g = 0; g < 4; ++g) az[Mt][g] = (f32x4){0.f, 0.f, 0.f, 0.f};
#pragma unroll
        for (int g = 0; g < 4; ++g) {
            int ntile = g * 4 + w;
            bf16x8 Aw[8];
#pragma unroll
            for (int kt = 0; kt < 8; ++kt)
                Aw[kt] = *(const bf16x8*)&wz[fidx(ntile, kt, q, ln, 8)];
#pragma unroll
            for (int Mt = 0; Mt < 4; ++Mt) {
                if (Mt < Mtn) {
                    f32x4 acc = az[Mt][g];
                    acc = __builtin_amdgcn_mfma_f32_16x16x32_bf16(
                        Aw[0], *(const bf16x8*)&s_hH[fidx(Mt, 0, q, ln, 2)], acc, 0, 0, 0);
                    acc = __builtin_amdgcn_mfma_f32_16x16x32_bf16(
                        Aw[1], *(const bf16x8*)&s_hH[fidx(Mt, 1, q, ln, 2)], acc, 0, 0, 0);
#pragma unroll
                    for (int kt = 0; kt < 6; ++kt)
                        acc = __builtin_amdgcn_mfma_f32_16x16x32_bf16(
                            Aw[2 + kt], *(const bf16x8*)&s_hhu[fidx(Mt, kt, q, ln, 6)], acc, 0, 0, 0);
                    az[Mt][g] = acc;
                }
            }
        }
        int colbase = w * 16 + q * 4;
        f32x4 bz0 = *(const f32x4*)&bzs[colbase];
        f32x4 bz1 = *(const f32x4*)&bzs[64 + colbase];
        f32x4 bz2 = *(const f32x4*)&bzs[128 + colbase];
        f32x4 bz3 = *(const f32x4*)&bzs[192 + colbase];
#pragma unroll
        for (int Mt = 0; Mt < 4; ++Mt) {
            if (Mt < Mtn) {
                int aH = fidx(Mt, colbase >> 5, (colbase >> 3) & 3, ln, 2) + (colbase & 7);
                int a0 = fidx(Mt, colbase >> 5, (colbase >> 3) & 3, ln, 6) + (colbase & 7);
                int c1 = 64 + colbase, c2 = 128 + colbase;
                int a1 = fidx(Mt, c1 >> 5, (c1 >> 3) & 3, ln, 6) + (c1 & 7);
                int a2 = fidx(Mt, c2 >> 5, (c2 >> 3) & 3, ln, 6) + (c2 & 7);
                int row = Mt * 16 + ln;
                if (row < rows) {
                    ushort hHv[4], u0[4], u1[4], u2[4];
                    *(uint2*)hHv = *(const uint2*)&s_hH[aH];
                    *(uint2*)u0 = *(const uint2*)&s_hhu[a0];
                    *(uint2*)u1 = *(const uint2*)&s_hhu[a1];
                    *(uint2*)u2 = *(const uint2*)&s_hhu[a2];
                    ushort ov[4]; float of[4];
#pragma unroll
                    for (int r = 0; r < 4; ++r) {
                        float e0 = fexp2(az[Mt][0][r] + bz0[r]);
                        float e1 = fexp2(az[Mt][1][r] + bz1[r]);
                        float e2 = fexp2(az[Mt][2][r] + bz2[r]);
                        float e3 = fexp2(az[Mt][3][r] + bz3[r]);
                        float inv = frcp(e0 + e1 + e2 + e3);
                        float v = (e0 * bfr2f(hHv[r]) + e1 * bfr2f(u0[r]) +
                                   e2 * bfr2f(u1[r]) + e3 * bfr2f(u2[r])) * inv;
                        ov[r] = f2bfr(v); of[r] = v;
                    }
                    size_t grow = (size_t)(row0 + row);
                    *(uint2*)&u_io[grow * 64 + colbase] = *(const uint2*)ov;
                    if (outp) *(float4*)&outp[grow * 64 + colbase] = *(const float4*)of;
                }
            }
        }
    }
}

__global__ __launch_bounds__(256, 3) void level_kernel(
    const bfr* __restrict__ ch, bfr* __restrict__ u_io,
    const bfr* __restrict__ wr, const float* __restrict__ brs,
    const bfr* __restrict__ wh, const float* __restrict__ b_h,
    const bfr* __restrict__ wz, const float* __restrict__ bzs)
{
    __shared__ bfr s_hhu[12288];
    __shared__ bfr s_t[12288];
    process_level(blockIdx.x * 64, 64, ch, u_io, wr, brs, wh, b_h, wz, bzs,
                  nullptr, s_hhu, s_t);
}

// levels j=5..0 fused, B=32 blocks, nested slices: block b's level-j reads are
// exactly its own level-(j+1) writes -> chain with __syncthreads only.
// Weight demand 32 blocks x ~224KB x 6 levels = 43MB, L2-hot after the j=6
// launch (R6 lesson: 256-block x 7-level fusion thrashed HBM at 189MB).
__global__ __launch_bounds__(256, 3) void fused32(
    bfr* __restrict__ u_all,
    const bfr* __restrict__ wr, const float* __restrict__ brs,
    const bfr* __restrict__ wh, const float* __restrict__ b_h,
    const bfr* __restrict__ wz, const float* __restrict__ bzs,
    float* __restrict__ outp)
{
    __shared__ bfr s_hhu[12288];
    __shared__ bfr s_t[12288];
    for (int j = 5; j >= 0; --j) {
        int rows = 2 << j;   // 64*2^j rows / 32 blocks
        process_level(blockIdx.x * rows, rows,
                      u_all + lvloff(j + 1), u_all + lvloff(j),
                      wr, brs, wh, b_h, wz, bzs,
                      (j == 0) ? outp : nullptr, s_hhu, s_t);
    }
}

extern "C" void kernel_launch(void* const* d_in, const int* in_sizes, int n_in,
                              void* d_out, int out_size, void* d_ws, size_t ws_size,
                              hipStream_t stream) {
    const float* contents = (const float*)d_in[0];
    const float* W_u = (const float*)d_in[1];
    const float* b_u = (const float*)d_in[2];
    const float* W_r = (const float*)d_in[3];
    const float* b_r = (const float*)d_in[4];
    const float* W_h = (const float*)d_in[5];
    const float* b_h = (const float*)d_in[6];
    const float* W_z = (const float*)d_in[7];
    const float* b_z = (const float*)d_in[8];
    float* out = (float*)d_out;

    // ws layout: u_all (524224 rows x 64, bf16; levels overwritten in-place
    // with their up) | wr | wh | wz | brs | bzs  -> ~67.3 MB total
    bfr* u_all = (bfr*)d_ws;
    bfr* wr = u_all + (size_t)524224 * 64;   // 33,550,336 elems
    bfr* wh = wr + 36864;
    bfr* wz = wh + 12288;
    float* brs = (float*)(wz + 65536);
    float* bzs = brs + 192;

    convert_weights<<<256, 256, 0, stream>>>(W_r, W_h, W_z, b_r, b_z,
                                             wr, wh, wz, brs, bzs);
    u_kernel<<<16382, 256, 0, stream>>>(contents, W_u, b_u, u_all);

    // levels 11..6: one 64-row tile per block, one launch per level
    for (int j = 11; j >= 6; --j) {
        level_kernel<<<1 << j, 256, 0, stream>>>(
            u_all + lvloff(j + 1), u_all + lvloff(j),
            wr, brs, wh, b_h, wz, bzs);
    }
    // levels 5..0: fused tail
    fused32<<<32, 256, 0, stream>>>(u_all, wr, brs, wh, b_h, wz, bzs, out);
}

// Round 9
// 271.357 us; speedup vs baseline: 1.6289x; 1.3015x over previous
//
#include <hip/hip_runtime.h>
#include <hip/hip_bf16.h>

// GRNNTransformGated, round 8.
// Post-mortem ledger:
//  R4: agent-scope spin grid barriers ~137us each -> never.
//  R6: B=256 x 7-level fusion refetched weights (189MB HBM) -> failed.
//  R7: fused32 tail = 100us at 0.4% MfmaUtil: pure latency chain; each wave
//      re-loads 56 weight frags from L2 EVERY level.
//  R8 fix: weights live in REGISTERS across levels. __launch_bounds__(256,1)
//      grants 512 VGPR/wave; 56 frags = 224 VGPR + ~90 working < 450 spill
//      threshold. B=256 fusion is now safe (no weight traffic at all).
//      fused_mid_regs: j=8..2, B=256. fused_tail_regs: j=1..0, B=64.
//      Nested slices: block b's level-j reads are its own level-(j+1) writes.
// Carried: u_all precompute; in-place up (level j output overwrites its u
// region); exp2-folded W_r/b_r/W_z/b_z; operand-swapped MFMA (D = W @ act^T,
// lane gets 4 consecutive out-cols of one row -> b64 epilogues).

#define LOG2E 1.4426950408889634f

typedef __bf16 bf16x8 __attribute__((ext_vector_type(8)));
typedef float f32x4 __attribute__((ext_vector_type(4)));
typedef unsigned short bfr;   // raw bf16 bits

__device__ __forceinline__ float bfr2f(bfr v) { return __uint_as_float(((unsigned)v) << 16); }
__device__ __forceinline__ bfr f2bfr(float f) {
    __hip_bfloat16 h = __float2bfloat16(f);
    return __builtin_bit_cast(bfr, h);
}
__device__ __forceinline__ float fexp2(float x) {
#if __has_builtin(__builtin_amdgcn_exp2f)
    return __builtin_amdgcn_exp2f(x);
#else
    return exp2f(x);
#endif
}
__device__ __forceinline__ float frcp(float x) {
#if __has_builtin(__builtin_amdgcn_rcpf)
    return __builtin_amdgcn_rcpf(x);
#else
    return 1.f / x;
#endif
}

// fragment-order address (elements): frag (Mt,kt), lane (ln,q), 8 elems
__device__ __forceinline__ int fidx(int Mt, int kt, int q, int ln, int KT) {
    return ((((Mt * KT + kt) * 4 + q) * 16 + ln) * 8);
}

// level-j region start (elements) within u_all: rows 64*(2^j-1), 64 cols
__device__ __host__ __forceinline__ size_t lvloff(int j) {
    return (size_t)((64 << j) - 64) * 64;
}

__device__ __forceinline__ void pack_one(const float* __restrict__ W, bfr* __restrict__ dst,
                                         int d, int K, float scale) {
    int KT = K >> 5;
    int j = d & 7, lnc = (d >> 3) & 15, q = (d >> 7) & 3;
    int t1 = d >> 9;
    int kt = t1 % KT, ntile = t1 / KT;
    int ncol = ntile * 16 + lnc;
    int k = kt * 32 + q * 8 + j;
    dst[d] = f2bfr(W[(size_t)ncol * K + k] * scale);
}

__global__ void convert_weights(const float* __restrict__ Wr, const float* __restrict__ Wh,
                                const float* __restrict__ Wz,
                                const float* __restrict__ br, const float* __restrict__ bz,
                                bfr* __restrict__ wr, bfr* __restrict__ wh, bfr* __restrict__ wz,
                                float* __restrict__ brs, float* __restrict__ bzs) {
    int i = blockIdx.x * 256 + threadIdx.x;   // grid covers 65536
    if (i < 36864) pack_one(Wr, wr, i, 192, LOG2E);
    if (i < 12288) pack_one(Wh, wh, i, 192, 1.f);
    if (i < 65536) pack_one(Wz, wz, i, 256, LOG2E);
    if (i < 192) brs[i] = br[i] * LOG2E;
    if (i < 256) bzs[i] = bz[i] * LOG2E;
}

// u = relu(contents @ W_u^T + b_u) for ALL 524224 rows.
// thread -> 2 output cols x 4 rows: 14 weight floats live (no spill).
__global__ void u_kernel(const float* __restrict__ contents,
                         const float* __restrict__ W_u, const float* __restrict__ b_u,
                         bfr* __restrict__ u_all) {
    int t = blockIdx.x * 256 + threadIdx.x;
    int row0 = (t >> 5) * 4, o0 = (t & 31) * 2;
    float w0[7], w1[7];
#pragma unroll
    for (int k = 0; k < 7; ++k) { w0[k] = W_u[o0 * 7 + k]; w1[k] = W_u[o0 * 7 + 7 + k]; }
    float bb0 = b_u[o0], bb1 = b_u[o0 + 1];
#pragma unroll
    for (int rr = 0; rr < 4; ++rr) {
        const float* cp = contents + (size_t)(row0 + rr) * 7;
        float a0 = bb0, a1 = bb1;
#pragma unroll
        for (int k = 0; k < 7; ++k) { float c = cp[k]; a0 += c * w0[k]; a1 += c * w1[k]; }
        ushort2 uv;
        uv.x = f2bfr(fmaxf(a0, 0.f));
        uv.y = f2bfr(fmaxf(a1, 0.f));
        *(ushort2*)&u_all[(size_t)(row0 + rr) * 64 + o0] = uv;
    }
}

// ---------------- occupancy-optimized per-level tile (j=11..9) --------------
__device__ __forceinline__ void process_level(
    int row0, int rows,
    const bfr* __restrict__ ch, bfr* __restrict__ u_io,
    const bfr* __restrict__ wr, const float* __restrict__ brs,
    const bfr* __restrict__ wh, const float* __restrict__ b_h,
    const bfr* __restrict__ wz, const float* __restrict__ bzs,
    float* __restrict__ outp,
    bfr* s_hhu, bfr* s_t)
{
    bfr* s_hH = s_t;   // aliased; h_H written only after all s_t reads done
    const int tid = threadIdx.x;
    const int lane = tid & 63, w = tid >> 6;
    const int ln = lane & 15, q = lane >> 4;
    const int Mtn = (rows + 15) >> 4;

    __syncthreads();

    // ---- stage hhu in fragment order ----
#pragma unroll
    for (int it = 0; it < 6; ++it) {
        int idx = it * 256 + tid;
        if (it < 4) {
            int lns = idx & 15, qs = (idx >> 4) & 3, kts = (idx >> 6) & 3, Mts = idx >> 8;
            int row = Mts * 16 + lns;
            if (row < rows) {
                int k = kts * 32 + qs * 8;
                const bfr* src = (k < 64)
                    ? ch + (size_t)(2 * (row0 + row)) * 64 + k
                    : ch + (size_t)(2 * (row0 + row) + 1) * 64 + (k - 64);
                *(uint4*)&s_hhu[fidx(Mts, kts, qs, lns, 6)] = *(const uint4*)src;
            }
        } else {
            int idx2 = idx - 1024;
            int lns = idx2 & 15, qs = (idx2 >> 4) & 3, ktl = (idx2 >> 6) & 1, Mts = (idx2 >> 7) & 3;
            int row = Mts * 16 + lns;
            if (row < rows) {
                int o0 = ktl * 32 + qs * 8;
                *(uint4*)&s_hhu[fidx(Mts, 4 + ktl, qs, lns, 6)] =
                    *(const uint4*)&u_io[(size_t)(row0 + row) * 64 + o0];
            }
        }
    }
    __syncthreads();

    // ---- mm1 ----
    {
        bf16x8 Af[3][6];
#pragma unroll
        for (int nt = 0; nt < 3; ++nt)
#pragma unroll
            for (int kt = 0; kt < 6; ++kt)
                Af[nt][kt] = *(const bf16x8*)&wr[fidx(w * 3 + nt, kt, q, ln, 6)];
#pragma unroll
        for (int Mt = 0; Mt < 4; ++Mt) {
            if (Mt < Mtn) {
                bf16x8 Bf[6];
#pragma unroll
                for (int kt = 0; kt < 6; ++kt)
                    Bf[kt] = *(const bf16x8*)&s_hhu[fidx(Mt, kt, q, ln, 6)];
#pragma unroll
                for (int nt = 0; nt < 3; ++nt) {
                    int colbase = (w * 3 + nt) * 16 + q * 4;
                    f32x4 acc = {0.f, 0.f, 0.f, 0.f};
#pragma unroll
                    for (int kt = 0; kt < 6; ++kt)
                        acc = __builtin_amdgcn_mfma_f32_16x16x32_bf16(Af[nt][kt], Bf[kt], acc, 0, 0, 0);
                    f32x4 br4 = *(const f32x4*)&brs[colbase];
                    int addr = fidx(Mt, colbase >> 5, (colbase >> 3) & 3, ln, 6) + (colbase & 7);
                    ushort hh[4], tt[4];
                    *(uint2*)hh = *(const uint2*)&s_hhu[addr];
#pragma unroll
                    for (int r = 0; r < 4; ++r) {
                        float e = fexp2(-(acc[r] + br4[r]));
                        tt[r] = f2bfr(frcp(1.f + e) * bfr2f(hh[r]));
                    }
                    *(uint2*)&s_t[addr] = *(const uint2*)tt;
                }
            }
        }
    }
    __syncthreads();

    // ---- mm2 ----
    f32x4 hacc[4];
    {
        bf16x8 Ah[6];
#pragma unroll
        for (int kt = 0; kt < 6; ++kt)
            Ah[kt] = *(const bf16x8*)&wh[fidx(w, kt, q, ln, 6)];
#pragma unroll
        for (int Mt = 0; Mt < 4; ++Mt) {
            if (Mt < Mtn) {
                f32x4 acc = {0.f, 0.f, 0.f, 0.f};
#pragma unroll
                for (int kt = 0; kt < 6; ++kt) {
                    bf16x8 Bf = *(const bf16x8*)&s_t[fidx(Mt, kt, q, ln, 6)];
                    acc = __builtin_amdgcn_mfma_f32_16x16x32_bf16(Ah[kt], Bf, acc, 0, 0, 0);
                }
                hacc[Mt] = acc;
            }
        }
    }
    __syncthreads();
    {
        int colbase = w * 16 + q * 4;
        f32x4 bh4 = *(const f32x4*)&b_h[colbase];
#pragma unroll
        for (int Mt = 0; Mt < 4; ++Mt) {
            if (Mt < Mtn) {
                int addr = fidx(Mt, colbase >> 5, (colbase >> 3) & 3, ln, 2) + (colbase & 7);
                ushort hv[4];
#pragma unroll
                for (int r = 0; r < 4; ++r) hv[r] = f2bfr(fmaxf(hacc[Mt][r] + bh4[r], 0.f));
                *(uint2*)&s_hH[addr] = *(const uint2*)hv;
            }
        }
    }
    __syncthreads();

    // ---- mm3 ----
    {
        f32x4 az[4][4];
#pragma unroll
        for (int Mt = 0; Mt < 4; ++Mt)
#pragma unroll
            for (int g = 0; g < 4; ++g) az[Mt][g] = (f32x4){0.f, 0.f, 0.f, 0.f};
#pragma unroll
        for (int g = 0; g < 4; ++g) {
            int ntile = g * 4 + w;
            bf16x8 Aw[8];
#pragma unroll
            for (int kt = 0; kt < 8; ++kt)
                Aw[kt] = *(const bf16x8*)&wz[fidx(ntile, kt, q, ln, 8)];
#pragma unroll
            for (int Mt = 0; Mt < 4; ++Mt) {
                if (Mt < Mtn) {
                    f32x4 acc = az[Mt][g];
                    acc = __builtin_amdgcn_mfma_f32_16x16x32_bf16(
                        Aw[0], *(const bf16x8*)&s_hH[fidx(Mt, 0, q, ln, 2)], acc, 0, 0, 0);
                    acc = __builtin_amdgcn_mfma_f32_16x16x32_bf16(
                        Aw[1], *(const bf16x8*)&s_hH[fidx(Mt, 1, q, ln, 2)], acc, 0, 0, 0);
#pragma unroll
                    for (int kt = 0; kt < 6; ++kt)
                        acc = __builtin_amdgcn_mfma_f32_16x16x32_bf16(
                            Aw[2 + kt], *(const bf16x8*)&s_hhu[fidx(Mt, kt, q, ln, 6)], acc, 0, 0, 0);
                    az[Mt][g] = acc;
                }
            }
        }
        int colbase = w * 16 + q * 4;
        f32x4 bz0 = *(const f32x4*)&bzs[colbase];
        f32x4 bz1 = *(const f32x4*)&bzs[64 + colbase];
        f32x4 bz2 = *(const f32x4*)&bzs[128 + colbase];
        f32x4 bz3 = *(const f32x4*)&bzs[192 + colbase];
#pragma unroll
        for (int Mt = 0; Mt < 4; ++Mt) {
            if (Mt < Mtn) {
                int aH = fidx(Mt, colbase >> 5, (colbase >> 3) & 3, ln, 2) + (colbase & 7);
                int a0 = fidx(Mt, colbase >> 5, (colbase >> 3) & 3, ln, 6) + (colbase & 7);
                int c1 = 64 + colbase, c2 = 128 + colbase;
                int a1 = fidx(Mt, c1 >> 5, (c1 >> 3) & 3, ln, 6) + (c1 & 7);
                int a2 = fidx(Mt, c2 >> 5, (c2 >> 3) & 3, ln, 6) + (c2 & 7);
                int row = Mt * 16 + ln;
                if (row < rows) {
                    ushort hHv[4], u0[4], u1[4], u2[4];
                    *(uint2*)hHv = *(const uint2*)&s_hH[aH];
                    *(uint2*)u0 = *(const uint2*)&s_hhu[a0];
                    *(uint2*)u1 = *(const uint2*)&s_hhu[a1];
                    *(uint2*)u2 = *(const uint2*)&s_hhu[a2];
                    ushort ov[4]; float of[4];
#pragma unroll
                    for (int r = 0; r < 4; ++r) {
                        float e0 = fexp2(az[Mt][0][r] + bz0[r]);
                        float e1 = fexp2(az[Mt][1][r] + bz1[r]);
                        float e2 = fexp2(az[Mt][2][r] + bz2[r]);
                        float e3 = fexp2(az[Mt][3][r] + bz3[r]);
                        float inv = frcp(e0 + e1 + e2 + e3);
                        float v = (e0 * bfr2f(hHv[r]) + e1 * bfr2f(u0[r]) +
                                   e2 * bfr2f(u1[r]) + e3 * bfr2f(u2[r])) * inv;
                        ov[r] = f2bfr(v); of[r] = v;
                    }
                    size_t grow = (size_t)(row0 + row);
                    *(uint2*)&u_io[grow * 64 + colbase] = *(const uint2*)ov;
                    if (outp) *(float4*)&outp[grow * 64 + colbase] = *(const float4*)of;
                }
            }
        }
    }
}

__global__ __launch_bounds__(256, 3) void level_kernel(
    const bfr* __restrict__ ch, bfr* __restrict__ u_io,
    const bfr* __restrict__ wr, const float* __restrict__ brs,
    const bfr* __restrict__ wh, const float* __restrict__ b_h,
    const bfr* __restrict__ wz, const float* __restrict__ bzs)
{
    __shared__ bfr s_hhu[12288];
    __shared__ bfr s_t[12288];
    process_level(blockIdx.x * 64, 64, ch, u_io, wr, brs, wh, b_h, wz, bzs,
                  nullptr, s_hhu, s_t);
}

// ---------------- register-persistent-weight variant (low-parallelism) -----
__device__ __forceinline__ void load_wregs(
    const bfr* __restrict__ wr, const bfr* __restrict__ wh, const bfr* __restrict__ wz,
    int w, int q, int ln,
    bf16x8 (&Af)[3][6], bf16x8 (&Ah)[6], bf16x8 (&Aw)[4][8])
{
#pragma unroll
    for (int nt = 0; nt < 3; ++nt)
#pragma unroll
        for (int kt = 0; kt < 6; ++kt)
            Af[nt][kt] = *(const bf16x8*)&wr[fidx(w * 3 + nt, kt, q, ln, 6)];
#pragma unroll
    for (int kt = 0; kt < 6; ++kt)
        Ah[kt] = *(const bf16x8*)&wh[fidx(w, kt, q, ln, 6)];
#pragma unroll
    for (int g = 0; g < 4; ++g)
#pragma unroll
        for (int kt = 0; kt < 8; ++kt)
            Aw[g][kt] = *(const bf16x8*)&wz[fidx(g * 4 + w, kt, q, ln, 8)];
}

__device__ __forceinline__ void process_level_regs(
    int row0, int rows,
    const bfr* __restrict__ ch, bfr* __restrict__ u_io,
    const bf16x8 (&Af)[3][6], const bf16x8 (&Ah)[6], const bf16x8 (&Aw)[4][8],
    const float* __restrict__ brs, const float* __restrict__ b_h,
    const float* __restrict__ bzs,
    float* __restrict__ outp, bfr* s_hhu, bfr* s_t)
{
    bfr* s_hH = s_t;
    const int tid = threadIdx.x;
    const int lane = tid & 63, w = tid >> 6;
    const int ln = lane & 15, q = lane >> 4;
    const int Mtn = (rows + 15) >> 4;

    __syncthreads();

    // ---- stage ----
#pragma unroll
    for (int it = 0; it < 6; ++it) {
        int idx = it * 256 + tid;
        if (it < 4) {
            int lns = idx & 15, qs = (idx >> 4) & 3, kts = (idx >> 6) & 3, Mts = idx >> 8;
            int row = Mts * 16 + lns;
            if (row < rows) {
                int k = kts * 32 + qs * 8;
                const bfr* src = (k < 64)
                    ? ch + (size_t)(2 * (row0 + row)) * 64 + k
                    : ch + (size_t)(2 * (row0 + row) + 1) * 64 + (k - 64);
                *(uint4*)&s_hhu[fidx(Mts, kts, qs, lns, 6)] = *(const uint4*)src;
            }
        } else {
            int idx2 = idx - 1024;
            int lns = idx2 & 15, qs = (idx2 >> 4) & 3, ktl = (idx2 >> 6) & 1, Mts = (idx2 >> 7) & 3;
            int row = Mts * 16 + lns;
            if (row < rows) {
                int o0 = ktl * 32 + qs * 8;
                *(uint4*)&s_hhu[fidx(Mts, 4 + ktl, qs, lns, 6)] =
                    *(const uint4*)&u_io[(size_t)(row0 + row) * 64 + o0];
            }
        }
    }
    __syncthreads();

    // ---- mm1 (weights from regs) ----
#pragma unroll
    for (int Mt = 0; Mt < 4; ++Mt) {
        if (Mt < Mtn) {
            bf16x8 Bf[6];
#pragma unroll
            for (int kt = 0; kt < 6; ++kt)
                Bf[kt] = *(const bf16x8*)&s_hhu[fidx(Mt, kt, q, ln, 6)];
#pragma unroll
            for (int nt = 0; nt < 3; ++nt) {
                int colbase = (w * 3 + nt) * 16 + q * 4;
                f32x4 acc = {0.f, 0.f, 0.f, 0.f};
#pragma unroll
                for (int kt = 0; kt < 6; ++kt)
                    acc = __builtin_amdgcn_mfma_f32_16x16x32_bf16(Af[nt][kt], Bf[kt], acc, 0, 0, 0);
                f32x4 br4 = *(const f32x4*)&brs[colbase];
                int addr = fidx(Mt, colbase >> 5, (colbase >> 3) & 3, ln, 6) + (colbase & 7);
                ushort hh[4], tt[4];
                *(uint2*)hh = *(const uint2*)&s_hhu[addr];
#pragma unroll
                for (int r = 0; r < 4; ++r) {
                    float e = fexp2(-(acc[r] + br4[r]));
                    tt[r] = f2bfr(frcp(1.f + e) * bfr2f(hh[r]));
                }
                *(uint2*)&s_t[addr] = *(const uint2*)tt;
            }
        }
    }
    __syncthreads();

    // ---- mm2 ----
    f32x4 hacc[4];
#pragma unroll
    for (int Mt = 0; Mt < 4; ++Mt) {
        if (Mt < Mtn) {
            f32x4 acc = {0.f, 0.f, 0.f, 0.f};
#pragma unroll
            for (int kt = 0; kt < 6; ++kt) {
                bf16x8 Bf = *(const bf16x8*)&s_t[fidx(Mt, kt, q, ln, 6)];
                acc = __builtin_amdgcn_mfma_f32_16x16x32_bf16(Ah[kt], Bf, acc, 0, 0, 0);
            }
            hacc[Mt] = acc;
        }
    }
    __syncthreads();
    {
        int colbase = w * 16 + q * 4;
        f32x4 bh4 = *(const f32x4*)&b_h[colbase];
#pragma unroll
        for (int Mt = 0; Mt < 4; ++Mt) {
            if (Mt < Mtn) {
                int addr = fidx(Mt, colbase >> 5, (colbase >> 3) & 3, ln, 2) + (colbase & 7);
                ushort hv[4];
#pragma unroll
                for (int r = 0; r < 4; ++r) hv[r] = f2bfr(fmaxf(hacc[Mt][r] + bh4[r], 0.f));
                *(uint2*)&s_hH[addr] = *(const uint2*)hv;
            }
        }
    }
    __syncthreads();

    // ---- mm3, per-Mt epilogue (bounds live accs to 16 regs) ----
    {
        int colbase = w * 16 + q * 4;
        f32x4 bz0 = *(const f32x4*)&bzs[colbase];
        f32x4 bz1 = *(const f32x4*)&bzs[64 + colbase];
        f32x4 bz2 = *(const f32x4*)&bzs[128 + colbase];
        f32x4 bz3 = *(const f32x4*)&bzs[192 + colbase];
#pragma unroll
        for (int Mt = 0; Mt < 4; ++Mt) {
            if (Mt < Mtn) {
                bf16x8 Az[8];
                Az[0] = *(const bf16x8*)&s_hH[fidx(Mt, 0, q, ln, 2)];
                Az[1] = *(const bf16x8*)&s_hH[fidx(Mt, 1, q, ln, 2)];
#pragma unroll
                for (int kt = 0; kt < 6; ++kt)
                    Az[2 + kt] = *(const bf16x8*)&s_hhu[fidx(Mt, kt, q, ln, 6)];
                f32x4 azg[4];
#pragma unroll
                for (int g = 0; g < 4; ++g) {
                    f32x4 acc = {0.f, 0.f, 0.f, 0.f};
#pragma unroll
                    for (int kt = 0; kt < 8; ++kt)
                        acc = __builtin_amdgcn_mfma_f32_16x16x32_bf16(Aw[g][kt], Az[kt], acc, 0, 0, 0);
                    azg[g] = acc;
                }
                int aH = fidx(Mt, colbase >> 5, (colbase >> 3) & 3, ln, 2) + (colbase & 7);
                int a0 = fidx(Mt, colbase >> 5, (colbase >> 3) & 3, ln, 6) + (colbase & 7);
                int c1 = 64 + colbase, c2 = 128 + colbase;
                int a1 = fidx(Mt, c1 >> 5, (c1 >> 3) & 3, ln, 6) + (c1 & 7);
                int a2 = fidx(Mt, c2 >> 5, (c2 >> 3) & 3, ln, 6) + (c2 & 7);
                int row = Mt * 16 + ln;
                if (row < rows) {
                    ushort hHv[4], u0[4], u1[4], u2[4];
                    *(uint2*)hHv = *(const uint2*)&s_hH[aH];
                    *(uint2*)u0 = *(const uint2*)&s_hhu[a0];
                    *(uint2*)u1 = *(const uint2*)&s_hhu[a1];
                    *(uint2*)u2 = *(const uint2*)&s_hhu[a2];
                    ushort ov[4]; float of[4];
#pragma unroll
                    for (int r = 0; r < 4; ++r) {
                        float e0 = fexp2(azg[0][r] + bz0[r]);
                        float e1 = fexp2(azg[1][r] + bz1[r]);
                        float e2 = fexp2(azg[2][r] + bz2[r]);
                        float e3 = fexp2(azg[3][r] + bz3[r]);
                        float inv = frcp(e0 + e1 + e2 + e3);
                        float v = (e0 * bfr2f(hHv[r]) + e1 * bfr2f(u0[r]) +
                                   e2 * bfr2f(u1[r]) + e3 * bfr2f(u2[r])) * inv;
                        ov[r] = f2bfr(v); of[r] = v;
                    }
                    size_t grow = (size_t)(row0 + row);
                    *(uint2*)&u_io[grow * 64 + colbase] = *(const uint2*)ov;
                    if (outp) *(float4*)&outp[grow * 64 + colbase] = *(const float4*)of;
                }
            }
        }
    }
}

// j=8..2, B=256 blocks; weights in regs the whole time -> zero weight traffic
// (R6's fusion failure mode eliminated). Nested slices: no grid sync.
__global__ __launch_bounds__(256, 1) void fused_mid_regs(
    bfr* __restrict__ u_all,
    const bfr* __restrict__ wr, const float* __restrict__ brs,
    const bfr* __restrict__ wh, const float* __restrict__ b_h,
    const bfr* __restrict__ wz, const float* __restrict__ bzs)
{
    __shared__ bfr s_hhu[12288];
    __shared__ bfr s_t[12288];
    const int tid = threadIdx.x;
    const int lane = tid & 63, w = tid >> 6, ln = lane & 15, q = lane >> 4;
    bf16x8 Af[3][6], Ah[6], Aw[4][8];
    load_wregs(wr, wh, wz, w, q, ln, Af, Ah, Aw);
    for (int j = 8; j >= 2; --j) {
        int rows = 1 << (j - 2);   // 64..1
        process_level_regs(blockIdx.x * rows, rows,
                           u_all + lvloff(j + 1), u_all + lvloff(j),
                           Af, Ah, Aw, brs, b_h, bzs, nullptr, s_hhu, s_t);
    }
}

// j=1..0, B=64 blocks.
__global__ __launch_bounds__(256, 1) void fused_tail_regs(
    bfr* __restrict__ u_all,
    const bfr* __restrict__ wr, const float* __restrict__ brs,
    const bfr* __restrict__ wh, const float* __restrict__ b_h,
    const bfr* __restrict__ wz, const float* __restrict__ bzs,
    float* __restrict__ outp)
{
    __shared__ bfr s_hhu[12288];
    __shared__ bfr s_t[12288];
    const int tid = threadIdx.x;
    const int lane = tid & 63, w = tid >> 6, ln = lane & 15, q = lane >> 4;
    bf16x8 Af[3][6], Ah[6], Aw[4][8];
    load_wregs(wr, wh, wz, w, q, ln, Af, Ah, Aw);
    for (int j = 1; j >= 0; --j) {
        int rows = 1 << j;         // 2, 1
        process_level_regs(blockIdx.x * rows, rows,
                           u_all + lvloff(j + 1), u_all + lvloff(j),
                           Af, Ah, Aw, brs, b_h, bzs,
                           (j == 0) ? outp : nullptr, s_hhu, s_t);
    }
}

extern "C" void kernel_launch(void* const* d_in, const int* in_sizes, int n_in,
                              void* d_out, int out_size, void* d_ws, size_t ws_size,
                              hipStream_t stream) {
    const float* contents = (const float*)d_in[0];
    const float* W_u = (const float*)d_in[1];
    const float* b_u = (const float*)d_in[2];
    const float* W_r = (const float*)d_in[3];
    const float* b_r = (const float*)d_in[4];
    const float* W_h = (const float*)d_in[5];
    const float* b_h = (const float*)d_in[6];
    const float* W_z = (const float*)d_in[7];
    const float* b_z = (const float*)d_in[8];
    float* out = (float*)d_out;

    // ws: u_all (524224 x 64 bf16, levels overwritten in-place) | wr|wh|wz|brs|bzs
    bfr* u_all = (bfr*)d_ws;
    bfr* wr = u_all + (size_t)524224 * 64;
    bfr* wh = wr + 36864;
    bfr* wz = wh + 12288;
    float* brs = (float*)(wz + 65536);
    float* bzs = brs + 192;

    convert_weights<<<256, 256, 0, stream>>>(W_r, W_h, W_z, b_r, b_z,
                                             wr, wh, wz, brs, bzs);
    u_kernel<<<16382, 256, 0, stream>>>(contents, W_u, b_u, u_all);

    // levels 11..9: throughput regime, one 64-row tile per block
    for (int j = 11; j >= 9; --j) {
        level_kernel<<<1 << j, 256, 0, stream>>>(
            u_all + lvloff(j + 1), u_all + lvloff(j),
            wr, brs, wh, b_h, wz, bzs);
    }
    // levels 8..2: fused, register-persistent weights
    fused_mid_regs<<<256, 256, 0, stream>>>(u_all, wr, brs, wh, b_h, wz, bzs);
    // levels 1..0
    fused_tail_regs<<<64, 256, 0, stream>>>(u_all, wr, brs, wh, b_h, wz, bzs, out);
}

// Round 10
// 261.737 us; speedup vs baseline: 1.6888x; 1.0368x over previous
//
#include <hip/hip_runtime.h>
#include <hip/hip_bf16.h>

// GRNNTransformGated, round 9.
// Post-mortem ledger:
//  R4: agent-scope spin grid barriers ~137us each -> never.
//  R6: B=256 x 7-level fusion refetched weights (189MB HBM) -> failed.
//  R7->R8: weights register-persistent across fused levels (launch_bounds
//      (256,1), 56 frags = 224 VGPR) -> tail fixed.
//  R8 profile: level_kernel WRITE_SIZE 120MB vs 16.8MB data (7x!). Cause:
//      epilogue uint2 stores put consecutive lanes at 128B stride (C-layout
//      lane->row), each 8B store dirties a full sector -> write amplification.
//      (Also retro-explains R5's WRITE 96MB.)
//  R9 fix: LDS round-trip for the up-store. Gate values computed in regs,
//      staged row-major into dead s_t (stride 76 elems: write side 2-way=free,
//      read side even), then cooperative store where consecutive lanes write
//      consecutive 16B -> full-line coalesced.
// Carried: u_all precompute; in-place up (level j output overwrites its u
// region); exp2-folded W_r/b_r/W_z/b_z; operand-swapped MFMA (D = W @ act^T,
// lane gets 4 consecutive out-cols of one row -> b64 LDS epilogues).

#define LOG2E 1.4426950408889634f
#define OSTR 76   // out-staging row stride (elements)

typedef __bf16 bf16x8 __attribute__((ext_vector_type(8)));
typedef float f32x4 __attribute__((ext_vector_type(4)));
typedef unsigned short bfr;   // raw bf16 bits

__device__ __forceinline__ float bfr2f(bfr v) { return __uint_as_float(((unsigned)v) << 16); }
__device__ __forceinline__ bfr f2bfr(float f) {
    __hip_bfloat16 h = __float2bfloat16(f);
    return __builtin_bit_cast(bfr, h);
}
__device__ __forceinline__ float fexp2(float x) {
#if __has_builtin(__builtin_amdgcn_exp2f)
    return __builtin_amdgcn_exp2f(x);
#else
    return exp2f(x);
#endif
}
__device__ __forceinline__ float frcp(float x) {
#if __has_builtin(__builtin_amdgcn_rcpf)
    return __builtin_amdgcn_rcpf(x);
#else
    return 1.f / x;
#endif
}

// fragment-order address (elements): frag (Mt,kt), lane (ln,q), 8 elems
__device__ __forceinline__ int fidx(int Mt, int kt, int q, int ln, int KT) {
    return ((((Mt * KT + kt) * 4 + q) * 16 + ln) * 8);
}

// level-j region start (elements) within u_all: rows 64*(2^j-1), 64 cols
__device__ __host__ __forceinline__ size_t lvloff(int j) {
    return (size_t)((64 << j) - 64) * 64;
}

__device__ __forceinline__ void pack_one(const float* __restrict__ W, bfr* __restrict__ dst,
                                         int d, int K, float scale) {
    int KT = K >> 5;
    int j = d & 7, lnc = (d >> 3) & 15, q = (d >> 7) & 3;
    int t1 = d >> 9;
    int kt = t1 % KT, ntile = t1 / KT;
    int ncol = ntile * 16 + lnc;
    int k = kt * 32 + q * 8 + j;
    dst[d] = f2bfr(W[(size_t)ncol * K + k] * scale);
}

__global__ void convert_weights(const float* __restrict__ Wr, const float* __restrict__ Wh,
                                const float* __restrict__ Wz,
                                const float* __restrict__ br, const float* __restrict__ bz,
                                bfr* __restrict__ wr, bfr* __restrict__ wh, bfr* __restrict__ wz,
                                float* __restrict__ brs, float* __restrict__ bzs) {
    int i = blockIdx.x * 256 + threadIdx.x;   // grid covers 65536
    if (i < 36864) pack_one(Wr, wr, i, 192, LOG2E);
    if (i < 12288) pack_one(Wh, wh, i, 192, 1.f);
    if (i < 65536) pack_one(Wz, wz, i, 256, LOG2E);
    if (i < 192) brs[i] = br[i] * LOG2E;
    if (i < 256) bzs[i] = bz[i] * LOG2E;
}

// u = relu(contents @ W_u^T + b_u) for ALL 524224 rows.
// thread -> 2 output cols x 4 rows: 14 weight floats live (no spill);
// stores coalesced (32 lanes cover a 128B row).
__global__ void u_kernel(const float* __restrict__ contents,
                         const float* __restrict__ W_u, const float* __restrict__ b_u,
                         bfr* __restrict__ u_all) {
    int t = blockIdx.x * 256 + threadIdx.x;
    int row0 = (t >> 5) * 4, o0 = (t & 31) * 2;
    float w0[7], w1[7];
#pragma unroll
    for (int k = 0; k < 7; ++k) { w0[k] = W_u[o0 * 7 + k]; w1[k] = W_u[o0 * 7 + 7 + k]; }
    float bb0 = b_u[o0], bb1 = b_u[o0 + 1];
#pragma unroll
    for (int rr = 0; rr < 4; ++rr) {
        const float* cp = contents + (size_t)(row0 + rr) * 7;
        float a0 = bb0, a1 = bb1;
#pragma unroll
        for (int k = 0; k < 7; ++k) { float c = cp[k]; a0 += c * w0[k]; a1 += c * w1[k]; }
        ushort2 uv;
        uv.x = f2bfr(fmaxf(a0, 0.f));
        uv.y = f2bfr(fmaxf(a1, 0.f));
        *(ushort2*)&u_all[(size_t)(row0 + rr) * 64 + o0] = uv;
    }
}

// Coalesced up-store epilogue: stage ovv (row-major, stride OSTR) into s_t
// (dead by now), then cooperative full-line store.
__device__ __forceinline__ void store_up_coalesced(
    int row0, int rows, bfr* __restrict__ u_io,
    const ushort (&ovv)[4][4], int Mtn, bfr* s_t)
{
    const int tid = threadIdx.x;
    const int lane = tid & 63, w = tid >> 6;
    const int ln = lane & 15, q = lane >> 4;
    const int colbase = w * 16 + q * 4;
    __syncthreads();   // all gate-input LDS reads complete -> s_t reusable
#pragma unroll
    for (int Mt = 0; Mt < 4; ++Mt) {
        if (Mt < Mtn) {
            int row = Mt * 16 + ln;
            if (row < rows)
                *(uint2*)&s_t[row * OSTR + colbase] = *(const uint2*)ovv[Mt];
        }
    }
    __syncthreads();
#pragma unroll
    for (int it = 0; it < 2; ++it) {
        int idx = it * 256 + tid;          // 8 chunks of 16B per 64-col row
        int row = idx >> 3, ck = idx & 7;
        if (row < rows)
            *(uint4*)&u_io[(size_t)(row0 + row) * 64 + ck * 8] =
                *(const uint4*)&s_t[row * OSTR + ck * 8];
    }
}

// ---------------- occupancy-optimized per-level tile (j=11..9) --------------
__device__ __forceinline__ void process_level(
    int row0, int rows,
    const bfr* __restrict__ ch, bfr* __restrict__ u_io,
    const bfr* __restrict__ wr, const float* __restrict__ brs,
    const bfr* __restrict__ wh, const float* __restrict__ b_h,
    const bfr* __restrict__ wz, const float* __restrict__ bzs,
    float* __restrict__ outp,
    bfr* s_hhu, bfr* s_t)
{
    bfr* s_hH = s_t;   // aliased; h_H written only after all s_t reads done
    const int tid = threadIdx.x;
    const int lane = tid & 63, w = tid >> 6;
    const int ln = lane & 15, q = lane >> 4;
    const int Mtn = (rows + 15) >> 4;

    __syncthreads();

    // ---- stage hhu in fragment order ----
#pragma unroll
    for (int it = 0; it < 6; ++it) {
        int idx = it * 256 + tid;
        if (it < 4) {
            int lns = idx & 15, qs = (idx >> 4) & 3, kts = (idx >> 6) & 3, Mts = idx >> 8;
            int row = Mts * 16 + lns;
            if (row < rows) {
                int k = kts * 32 + qs * 8;
                const bfr* src = (k < 64)
                    ? ch + (size_t)(2 * (row0 + row)) * 64 + k
                    : ch + (size_t)(2 * (row0 + row) + 1) * 64 + (k - 64);
                *(uint4*)&s_hhu[fidx(Mts, kts, qs, lns, 6)] = *(const uint4*)src;
            }
        } else {
            int idx2 = idx - 1024;
            int lns = idx2 & 15, qs = (idx2 >> 4) & 3, ktl = (idx2 >> 6) & 1, Mts = (idx2 >> 7) & 3;
            int row = Mts * 16 + lns;
            if (row < rows) {
                int o0 = ktl * 32 + qs * 8;
                *(uint4*)&s_hhu[fidx(Mts, 4 + ktl, qs, lns, 6)] =
                    *(const uint4*)&u_io[(size_t)(row0 + row) * 64 + o0];
            }
        }
    }
    __syncthreads();

    // ---- mm1 ----
    {
        bf16x8 Af[3][6];
#pragma unroll
        for (int nt = 0; nt < 3; ++nt)
#pragma unroll
            for (int kt = 0; kt < 6; ++kt)
                Af[nt][kt] = *(const bf16x8*)&wr[fidx(w * 3 + nt, kt, q, ln, 6)];
#pragma unroll
        for (int Mt = 0; Mt < 4; ++Mt) {
            if (Mt < Mtn) {
                bf16x8 Bf[6];
#pragma unroll
                for (int kt = 0; kt < 6; ++kt)
                    Bf[kt] = *(const bf16x8*)&s_hhu[fidx(Mt, kt, q, ln, 6)];
#pragma unroll
                for (int nt = 0; nt < 3; ++nt) {
                    int colbase = (w * 3 + nt) * 16 + q * 4;
                    f32x4 acc = {0.f, 0.f, 0.f, 0.f};
#pragma unroll
                    for (int kt = 0; kt < 6; ++kt)
                        acc = __builtin_amdgcn_mfma_f32_16x16x32_bf16(Af[nt][kt], Bf[kt], acc, 0, 0, 0);
                    f32x4 br4 = *(const f32x4*)&brs[colbase];
                    int addr = fidx(Mt, colbase >> 5, (colbase >> 3) & 3, ln, 6) + (colbase & 7);
                    ushort hh[4], tt[4];
                    *(uint2*)hh = *(const uint2*)&s_hhu[addr];
#pragma unroll
                    for (int r = 0; r < 4; ++r) {
                        float e = fexp2(-(acc[r] + br4[r]));
                        tt[r] = f2bfr(frcp(1.f + e) * bfr2f(hh[r]));
                    }
                    *(uint2*)&s_t[addr] = *(const uint2*)tt;
                }
            }
        }
    }
    __syncthreads();

    // ---- mm2 ----
    f32x4 hacc[4];
    {
        bf16x8 Ah[6];
#pragma unroll
        for (int kt = 0; kt < 6; ++kt)
            Ah[kt] = *(const bf16x8*)&wh[fidx(w, kt, q, ln, 6)];
#pragma unroll
        for (int Mt = 0; Mt < 4; ++Mt) {
            if (Mt < Mtn) {
                f32x4 acc = {0.f, 0.f, 0.f, 0.f};
#pragma unroll
                for (int kt = 0; kt < 6; ++kt) {
                    bf16x8 Bf = *(const bf16x8*)&s_t[fidx(Mt, kt, q, ln, 6)];
                    acc = __builtin_amdgcn_mfma_f32_16x16x32_bf16(Ah[kt], Bf, acc, 0, 0, 0);
                }
                hacc[Mt] = acc;
            }
        }
    }
    __syncthreads();
    {
        int colbase = w * 16 + q * 4;
        f32x4 bh4 = *(const f32x4*)&b_h[colbase];
#pragma unroll
        for (int Mt = 0; Mt < 4; ++Mt) {
            if (Mt < Mtn) {
                int addr = fidx(Mt, colbase >> 5, (colbase >> 3) & 3, ln, 2) + (colbase & 7);
                ushort hv[4];
#pragma unroll
                for (int r = 0; r < 4; ++r) hv[r] = f2bfr(fmaxf(hacc[Mt][r] + bh4[r], 0.f));
                *(uint2*)&s_hH[addr] = *(const uint2*)hv;
            }
        }
    }
    __syncthreads();

    // ---- mm3 + gate (values to regs), then coalesced store ----
    {
        f32x4 az[4][4];
#pragma unroll
        for (int Mt = 0; Mt < 4; ++Mt)
#pragma unroll
            for (int g = 0; g < 4; ++g) az[Mt][g] = (f32x4){0.f, 0.f, 0.f, 0.f};
#pragma unroll
        for (int g = 0; g < 4; ++g) {
            int ntile = g * 4 + w;
            bf16x8 Aw[8];
#pragma unroll
            for (int kt = 0; kt < 8; ++kt)
                Aw[kt] = *(const bf16x8*)&wz[fidx(ntile, kt, q, ln, 8)];
#pragma unroll
            for (int Mt = 0; Mt < 4; ++Mt) {
                if (Mt < Mtn) {
                    f32x4 acc = az[Mt][g];
                    acc = __builtin_amdgcn_mfma_f32_16x16x32_bf16(
                        Aw[0], *(const bf16x8*)&s_hH[fidx(Mt, 0, q, ln, 2)], acc, 0, 0, 0);
                    acc = __builtin_amdgcn_mfma_f32_16x16x32_bf16(
                        Aw[1], *(const bf16x8*)&s_hH[fidx(Mt, 1, q, ln, 2)], acc, 0, 0, 0);
#pragma unroll
                    for (int kt = 0; kt < 6; ++kt)
                        acc = __builtin_amdgcn_mfma_f32_16x16x32_bf16(
                            Aw[2 + kt], *(const bf16x8*)&s_hhu[fidx(Mt, kt, q, ln, 6)], acc, 0, 0, 0);
                    az[Mt][g] = acc;
                }
            }
        }
        int colbase = w * 16 + q * 4;
        f32x4 bz0 = *(const f32x4*)&bzs[colbase];
        f32x4 bz1 = *(const f32x4*)&bzs[64 + colbase];
        f32x4 bz2 = *(const f32x4*)&bzs[128 + colbase];
        f32x4 bz3 = *(const f32x4*)&bzs[192 + colbase];
        ushort ovv[4][4];
#pragma unroll
        for (int Mt = 0; Mt < 4; ++Mt) {
            if (Mt < Mtn) {
                int aH = fidx(Mt, colbase >> 5, (colbase >> 3) & 3, ln, 2) + (colbase & 7);
                int a0 = fidx(Mt, colbase >> 5, (colbase >> 3) & 3, ln, 6) + (colbase & 7);
                int c1 = 64 + colbase, c2 = 128 + colbase;
                int a1 = fidx(Mt, c1 >> 5, (c1 >> 3) & 3, ln, 6) + (c1 & 7);
                int a2 = fidx(Mt, c2 >> 5, (c2 >> 3) & 3, ln, 6) + (c2 & 7);
                int row = Mt * 16 + ln;
                if (row < rows) {
                    ushort hHv[4], u0[4], u1[4], u2[4];
                    *(uint2*)hHv = *(const uint2*)&s_hH[aH];
                    *(uint2*)u0 = *(const uint2*)&s_hhu[a0];
                    *(uint2*)u1 = *(const uint2*)&s_hhu[a1];
                    *(uint2*)u2 = *(const uint2*)&s_hhu[a2];
                    float of[4];
#pragma unroll
                    for (int r = 0; r < 4; ++r) {
                        float e0 = fexp2(az[Mt][0][r] + bz0[r]);
                        float e1 = fexp2(az[Mt][1][r] + bz1[r]);
                        float e2 = fexp2(az[Mt][2][r] + bz2[r]);
                        float e3 = fexp2(az[Mt][3][r] + bz3[r]);
                        float inv = frcp(e0 + e1 + e2 + e3);
                        float v = (e0 * bfr2f(hHv[r]) + e1 * bfr2f(u0[r]) +
                                   e2 * bfr2f(u1[r]) + e3 * bfr2f(u2[r])) * inv;
                        ovv[Mt][r] = f2bfr(v); of[r] = v;
                    }
                    if (outp)
                        *(float4*)&outp[(size_t)(row0 + row) * 64 + colbase] = *(const float4*)of;
                }
            }
        }
        store_up_coalesced(row0, rows, u_io, ovv, Mtn, s_t);
    }
}

__global__ __launch_bounds__(256, 3) void level_kernel(
    const bfr* __restrict__ ch, bfr* __restrict__ u_io,
    const bfr* __restrict__ wr, const float* __restrict__ brs,
    const bfr* __restrict__ wh, const float* __restrict__ b_h,
    const bfr* __restrict__ wz, const float* __restrict__ bzs)
{
    __shared__ bfr s_hhu[12288];
    __shared__ bfr s_t[12288];
    process_level(blockIdx.x * 64, 64, ch, u_io, wr, brs, wh, b_h, wz, bzs,
                  nullptr, s_hhu, s_t);
}

// ---------------- register-persistent-weight variant (low-parallelism) -----
__device__ __forceinline__ void load_wregs(
    const bfr* __restrict__ wr, const bfr* __restrict__ wh, const bfr* __restrict__ wz,
    int w, int q, int ln,
    bf16x8 (&Af)[3][6], bf16x8 (&Ah)[6], bf16x8 (&Aw)[4][8])
{
#pragma unroll
    for (int nt = 0; nt < 3; ++nt)
#pragma unroll
        for (int kt = 0; kt < 6; ++kt)
            Af[nt][kt] = *(const bf16x8*)&wr[fidx(w * 3 + nt, kt, q, ln, 6)];
#pragma unroll
    for (int kt = 0; kt < 6; ++kt)
        Ah[kt] = *(const bf16x8*)&wh[fidx(w, kt, q, ln, 6)];
#pragma unroll
    for (int g = 0; g < 4; ++g)
#pragma unroll
        for (int kt = 0; kt < 8; ++kt)
            Aw[g][kt] = *(const bf16x8*)&wz[fidx(g * 4 + w, kt, q, ln, 8)];
}

__device__ __forceinline__ void process_level_regs(
    int row0, int rows,
    const bfr* __restrict__ ch, bfr* __restrict__ u_io,
    const bf16x8 (&Af)[3][6], const bf16x8 (&Ah)[6], const bf16x8 (&Aw)[4][8],
    const float* __restrict__ brs, const float* __restrict__ b_h,
    const float* __restrict__ bzs,
    float* __restrict__ outp, bfr* s_hhu, bfr* s_t)
{
    bfr* s_hH = s_t;
    const int tid = threadIdx.x;
    const int lane = tid & 63, w = tid >> 6;
    const int ln = lane & 15, q = lane >> 4;
    const int Mtn = (rows + 15) >> 4;

    __syncthreads();

    // ---- stage ----
#pragma unroll
    for (int it = 0; it < 6; ++it) {
        int idx = it * 256 + tid;
        if (it < 4) {
            int lns = idx & 15, qs = (idx >> 4) & 3, kts = (idx >> 6) & 3, Mts = idx >> 8;
            int row = Mts * 16 + lns;
            if (row < rows) {
                int k = kts * 32 + qs * 8;
                const bfr* src = (k < 64)
                    ? ch + (size_t)(2 * (row0 + row)) * 64 + k
                    : ch + (size_t)(2 * (row0 + row) + 1) * 64 + (k - 64);
                *(uint4*)&s_hhu[fidx(Mts, kts, qs, lns, 6)] = *(const uint4*)src;
            }
        } else {
            int idx2 = idx - 1024;
            int lns = idx2 & 15, qs = (idx2 >> 4) & 3, ktl = (idx2 >> 6) & 1, Mts = (idx2 >> 7) & 3;
            int row = Mts * 16 + lns;
            if (row < rows) {
                int o0 = ktl * 32 + qs * 8;
                *(uint4*)&s_hhu[fidx(Mts, 4 + ktl, qs, lns, 6)] =
                    *(const uint4*)&u_io[(size_t)(row0 + row) * 64 + o0];
            }
        }
    }
    __syncthreads();

    // ---- mm1 (weights from regs) ----
#pragma unroll
    for (int Mt = 0; Mt < 4; ++Mt) {
        if (Mt < Mtn) {
            bf16x8 Bf[6];
#pragma unroll
            for (int kt = 0; kt < 6; ++kt)
                Bf[kt] = *(const bf16x8*)&s_hhu[fidx(Mt, kt, q, ln, 6)];
#pragma unroll
            for (int nt = 0; nt < 3; ++nt) {
                int colbase = (w * 3 + nt) * 16 + q * 4;
                f32x4 acc = {0.f, 0.f, 0.f, 0.f};
#pragma unroll
                for (int kt = 0; kt < 6; ++kt)
                    acc = __builtin_amdgcn_mfma_f32_16x16x32_bf16(Af[nt][kt], Bf[kt], acc, 0, 0, 0);
                f32x4 br4 = *(const f32x4*)&brs[colbase];
                int addr = fidx(Mt, colbase >> 5, (colbase >> 3) & 3, ln, 6) + (colbase & 7);
                ushort hh[4], tt[4];
                *(uint2*)hh = *(const uint2*)&s_hhu[addr];
#pragma unroll
                for (int r = 0; r < 4; ++r) {
                    float e = fexp2(-(acc[r] + br4[r]));
                    tt[r] = f2bfr(frcp(1.f + e) * bfr2f(hh[r]));
                }
                *(uint2*)&s_t[addr] = *(const uint2*)tt;
            }
        }
    }
    __syncthreads();

    // ---- mm2 ----
    f32x4 hacc[4];
#pragma unroll
    for (int Mt = 0; Mt < 4; ++Mt) {
        if (Mt < Mtn) {
            f32x4 acc = {0.f, 0.f, 0.f, 0.f};
#pragma unroll
            for (int kt = 0; kt < 6; ++kt) {
                bf16x8 Bf = *(const bf16x8*)&s_t[fidx(Mt, kt, q, ln, 6)];
                acc = __builtin_amdgcn_mfma_f32_16x16x32_bf16(Ah[kt], Bf, acc, 0, 0, 0);
            }
            hacc[Mt] = acc;
        }
    }
    __syncthreads();
    {
        int colbase = w * 16 + q * 4;
        f32x4 bh4 = *(const f32x4*)&b_h[colbase];
#pragma unroll
        for (int Mt = 0; Mt < 4; ++Mt) {
            if (Mt < Mtn) {
                int addr = fidx(Mt, colbase >> 5, (colbase >> 3) & 3, ln, 2) + (colbase & 7);
                ushort hv[4];
#pragma unroll
                for (int r = 0; r < 4; ++r) hv[r] = f2bfr(fmaxf(hacc[Mt][r] + bh4[r], 0.f));
                *(uint2*)&s_hH[addr] = *(const uint2*)hv;
            }
        }
    }
    __syncthreads();

    // ---- mm3 per-Mt + gate to regs, then coalesced store ----
    {
        int colbase = w * 16 + q * 4;
        f32x4 bz0 = *(const f32x4*)&bzs[colbase];
        f32x4 bz1 = *(const f32x4*)&bzs[64 + colbase];
        f32x4 bz2 = *(const f32x4*)&bzs[128 + colbase];
        f32x4 bz3 = *(const f32x4*)&bzs[192 + colbase];
        ushort ovv[4][4];
#pragma unroll
        for (int Mt = 0; Mt < 4; ++Mt) {
            if (Mt < Mtn) {
                bf16x8 Az[8];
                Az[0] = *(const bf16x8*)&s_hH[fidx(Mt, 0, q, ln, 2)];
                Az[1] = *(const bf16x8*)&s_hH[fidx(Mt, 1, q, ln, 2)];
#pragma unroll
                for (int kt = 0; kt < 6; ++kt)
                    Az[2 + kt] = *(const bf16x8*)&s_hhu[fidx(Mt, kt, q, ln, 6)];
                f32x4 azg[4];
#pragma unroll
                for (int g = 0; g < 4; ++g) {
                    f32x4 acc = {0.f, 0.f, 0.f, 0.f};
#pragma unroll
                    for (int kt = 0; kt < 8; ++kt)
                        acc = __builtin_amdgcn_mfma_f32_16x16x32_bf16(Aw[g][kt], Az[kt], acc, 0, 0, 0);
                    azg[g] = acc;
                }
                int aH = fidx(Mt, colbase >> 5, (colbase >> 3) & 3, ln, 2) + (colbase & 7);
                int a0 = fidx(Mt, colbase >> 5, (colbase >> 3) & 3, ln, 6) + (colbase & 7);
                int c1 = 64 + colbase, c2 = 128 + colbase;
                int a1 = fidx(Mt, c1 >> 5, (c1 >> 3) & 3, ln, 6) + (c1 & 7);
                int a2 = fidx(Mt, c2 >> 5, (c2 >> 3) & 3, ln, 6) + (c2 & 7);
                int row = Mt * 16 + ln;
                if (row < rows) {
                    ushort hHv[4], u0[4], u1[4], u2[4];
                    *(uint2*)hHv = *(const uint2*)&s_hH[aH];
                    *(uint2*)u0 = *(const uint2*)&s_hhu[a0];
                    *(uint2*)u1 = *(const uint2*)&s_hhu[a1];
                    *(uint2*)u2 = *(const uint2*)&s_hhu[a2];
                    float of[4];
#pragma unroll
                    for (int r = 0; r < 4; ++r) {
                        float e0 = fexp2(azg[0][r] + bz0[r]);
                        float e1 = fexp2(azg[1][r] + bz1[r]);
                        float e2 = fexp2(azg[2][r] + bz2[r]);
                        float e3 = fexp2(azg[3][r] + bz3[r]);
                        float inv = frcp(e0 + e1 + e2 + e3);
                        float v = (e0 * bfr2f(hHv[r]) + e1 * bfr2f(u0[r]) +
                                   e2 * bfr2f(u1[r]) + e3 * bfr2f(u2[r])) * inv;
                        ovv[Mt][r] = f2bfr(v); of[r] = v;
                    }
                    if (outp)
                        *(float4*)&outp[(size_t)(row0 + row) * 64 + colbase] = *(const float4*)of;
                }
            }
        }
        store_up_coalesced(row0, rows, u_io, ovv, Mtn, s_t);
    }
}

// j=8..2, B=256 blocks; weights in regs across levels -> zero weight traffic.
// Nested slices: block b's level-j reads are its own level-(j+1) writes.
__global__ __launch_bounds__(256, 1) void fused_mid_regs(
    bfr* __restrict__ u_all,
    const bfr* __restrict__ wr, const float* __restrict__ brs,
    const bfr* __restrict__ wh, const float* __restrict__ b_h,
    const bfr* __restrict__ wz, const float* __restrict__ bzs)
{
    __shared__ bfr s_hhu[12288];
    __shared__ bfr s_t[12288];
    const int tid = threadIdx.x;
    const int lane = tid & 63, w = tid >> 6, ln = lane & 15, q = lane >> 4;
    bf16x8 Af[3][6], Ah[6], Aw[4][8];
    load_wregs(wr, wh, wz, w, q, ln, Af, Ah, Aw);
    for (int j = 8; j >= 2; --j) {
        int rows = 1 << (j - 2);   // 64..1
        process_level_regs(blockIdx.x * rows, rows,
                           u_all + lvloff(j + 1), u_all + lvloff(j),
                           Af, Ah, Aw, brs, b_h, bzs, nullptr, s_hhu, s_t);
    }
}

// j=1..0, B=64 blocks.
__global__ __launch_bounds__(256, 1) void fused_tail_regs(
    bfr* __restrict__ u_all,
    const bfr* __restrict__ wr, const float* __restrict__ brs,
    const bfr* __restrict__ wh, const float* __restrict__ b_h,
    const bfr* __restrict__ wz, const float* __restrict__ bzs,
    float* __restrict__ outp)
{
    __shared__ bfr s_hhu[12288];
    __shared__ bfr s_t[12288];
    const int tid = threadIdx.x;
    const int lane = tid & 63, w = tid >> 6, ln = lane & 15, q = lane >> 4;
    bf16x8 Af[3][6], Ah[6], Aw[4][8];
    load_wregs(wr, wh, wz, w, q, ln, Af, Ah, Aw);
    for (int j = 1; j >= 0; --j) {
        int rows = 1 << j;         // 2, 1
        process_level_regs(blockIdx.x * rows, rows,
                           u_all + lvloff(j + 1), u_all + lvloff(j),
                           Af, Ah, Aw, brs, b_h, bzs,
                           (j == 0) ? outp : nullptr, s_hhu, s_t);
    }
}

extern "C" void kernel_launch(void* const* d_in, const int* in_sizes, int n_in,
                              void* d_out, int out_size, void* d_ws, size_t ws_size,
                              hipStream_t stream) {
    const float* contents = (const float*)d_in[0];
    const float* W_u = (const float*)d_in[1];
    const float* b_u = (const float*)d_in[2];
    const float* W_r = (const float*)d_in[3];
    const float* b_r = (const float*)d_in[4];
    const float* W_h = (const float*)d_in[5];
    const float* b_h = (const float*)d_in[6];
    const float* W_z = (const float*)d_in[7];
    const float* b_z = (const float*)d_in[8];
    float* out = (float*)d_out;

    // ws: u_all (524224 x 64 bf16, levels overwritten in-place) | wr|wh|wz|brs|bzs
    bfr* u_all = (bfr*)d_ws;
    bfr* wr = u_all + (size_t)524224 * 64;
    bfr* wh = wr + 36864;
    bfr* wz = wh + 12288;
    float* brs = (float*)(wz + 65536);
    float* bzs = brs + 192;

    convert_weights<<<256, 256, 0, stream>>>(W_r, W_h, W_z, b_r, b_z,
                                             wr, wh, wz, brs, bzs);
    u_kernel<<<16382, 256, 0, stream>>>(contents, W_u, b_u, u_all);

    // levels 11..9: throughput regime, one 64-row tile per block
    for (int j = 11; j >= 9; --j) {
        level_kernel<<<1 << j, 256, 0, stream>>>(
            u_all + lvloff(j + 1), u_all + lvloff(j),
            wr, brs, wh, b_h, wz, bzs);
    }
    // levels 8..2: fused, register-persistent weights
    fused_mid_regs<<<256, 256, 0, stream>>>(u_all, wr, brs, wh, b_h, wz, bzs);
    // levels 1..0
    fused_tail_regs<<<64, 256, 0, stream>>>(u_all, wr, brs, wh, b_h, wz, bzs, out);
}